// Round 1
// baseline (89.371 us; speedup 1.0000x reference)
//
#include <hip/hip_runtime.h>

constexpr int IN_DIM  = 4 * 64 * 64;   // 16384
constexpr int OUT_CH  = 2;
constexpr int BLOCK   = 256;
constexpr int ITERS   = IN_DIM / 4 / BLOCK;  // 4096 float4 / 256 threads = 16

__global__ __launch_bounds__(BLOCK) void gender_classifier_kernel(
    const float* __restrict__ x,     // [B, IN_DIM]
    const int*   __restrict__ t,     // [B]
    const float* __restrict__ W,     // [50, OUT_CH, IN_DIM]
    const float* __restrict__ bias,  // [50, OUT_CH]
    float*       __restrict__ out)   // [B, OUT_CH]
{
    const int b   = blockIdx.x;
    const int tid = threadIdx.x;

    // TIMESTEPS[i] = 980 - 20*i  ->  i = (980 - t) / 20
    const int idx = (980 - t[b]) / 20;

    const float4* xv = reinterpret_cast<const float4*>(x + (size_t)b * IN_DIM);
    const float4* w0 = reinterpret_cast<const float4*>(W + (size_t)idx * (OUT_CH * IN_DIM));
    const float4* w1 = w0 + IN_DIM / 4;

    float acc0 = 0.0f, acc1 = 0.0f;
#pragma unroll
    for (int i = 0; i < ITERS; ++i) {
        const int j = tid + i * BLOCK;
        const float4 xv4 = xv[j];
        const float4 a   = w0[j];
        const float4 c   = w1[j];
        acc0 += xv4.x * a.x + xv4.y * a.y + xv4.z * a.z + xv4.w * a.w;
        acc1 += xv4.x * c.x + xv4.y * c.y + xv4.z * c.z + xv4.w * c.w;
    }

    // wave(64)-level butterfly reduce
    for (int off = 32; off > 0; off >>= 1) {
        acc0 += __shfl_down(acc0, off, 64);
        acc1 += __shfl_down(acc1, off, 64);
    }

    __shared__ float red[BLOCK / 64][2];
    const int wave = tid >> 6;
    if ((tid & 63) == 0) {
        red[wave][0] = acc0;
        red[wave][1] = acc1;
    }
    __syncthreads();

    if (tid == 0) {
        float s0 = red[0][0] + red[1][0] + red[2][0] + red[3][0];
        float s1 = red[0][1] + red[1][1] + red[2][1] + red[3][1];
        out[(size_t)b * OUT_CH + 0] = s0 + bias[idx * OUT_CH + 0];
        out[(size_t)b * OUT_CH + 1] = s1 + bias[idx * OUT_CH + 1];
    }
}

extern "C" void kernel_launch(void* const* d_in, const int* in_sizes, int n_in,
                              void* d_out, int out_size, void* d_ws, size_t ws_size,
                              hipStream_t stream) {
    const float* x    = (const float*)d_in[0];
    const int*   t    = (const int*)d_in[1];
    const float* W    = (const float*)d_in[2];
    const float* bias = (const float*)d_in[3];
    float*       out  = (float*)d_out;

    const int B = in_sizes[1];  // 4096 samples (t has one entry per sample)

    gender_classifier_kernel<<<B, BLOCK, 0, stream>>>(x, t, W, bias, out);
}